// Round 11
// baseline (618.214 us; speedup 1.0000x reference)
//
#include <hip/hip_runtime.h>
#include <hip/hip_bf16.h>

typedef unsigned short ushort_t;
typedef unsigned int uint_t;
typedef __attribute__((ext_vector_type(8))) short short8;
typedef __attribute__((ext_vector_type(4))) float f32x4;

#define DIMC 256
#define D_INNER 512
#define D_STATE 64
#define DT_RANK 16
#define LSEQ 4096
#define BS2 8            // 2*BS batches through mamba
#define MROWS (BS2*LSEQ) // 32768

// lane-bit permutation for the scan merge tree (v15-verified):
// t-bit b -> lane-xor bit pi(b): pi = {0,1,3,4,5,2}
__device__ __forceinline__ int perm_inv(int p) {
    return (p & 3) | ((p & 0x38) >> 1) | ((p & 4) << 3);
}

__device__ __forceinline__ float b2f(ushort_t u) {
    union { uint_t i; float f; } v; v.i = ((uint_t)u) << 16; return v.f;
}
__device__ __forceinline__ ushort_t f2b(float f) {
    union { float f; uint_t i; } v; v.f = f;
    uint_t r = v.i + 0x7FFFu + ((v.i >> 16) & 1u);   // RNE
    return (ushort_t)(r >> 16);
}

// async global->LDS 16B per lane (HW: wave-uniform LDS base + lane*16)
typedef __attribute__((address_space(1))) const unsigned int gas_u32;
typedef __attribute__((address_space(3))) unsigned int las_u32;
__device__ __forceinline__ void gload16(const void* g, void* l) {
    __builtin_amdgcn_global_load_lds((gas_u32*)g, (las_u32*)l, 16, 0, 0);
}

// XCD-aware block remap for GEMMs [v17/v18 measured: ~12us tail gain — kept]
__device__ __forceinline__ void xcd_remap(int gy, int ybits, int& mblk, int& nblk) {
    int idl = blockIdx.x + gridDim.x * blockIdx.y;
    int xcdc = idl & 7;
    int rest = idl >> 3;
    int y = rest & (gy - 1);
    int xhi = rest >> ybits;
    mblk = (xhi * 8 + xcdc) * 128;
    nblk = y * 128;
}

// ---------------- merged: LN1 + xm (SINGLE order; blocks 0..16383) + weight cvt ----------------
// v21: second (transposed-order) xm copy is no longer materialized — 67 MB of
// writes saved; gemm128_split remaps the source row at A-staging time instead.
__global__ void cvt_ln1(const float* __restrict__ x,
                        const float* __restrict__ w,
                        const float* __restrict__ bb,
                        ushort_t* __restrict__ xm,
                        const float* __restrict__ s0, ushort_t* __restrict__ d0,
                        const float* __restrict__ s1, ushort_t* __restrict__ d1,
                        const float* __restrict__ s2, ushort_t* __restrict__ d2) {
    if (blockIdx.x >= 16384) {
        int i = (blockIdx.x - 16384) * 256 + threadIdx.x;
        const int n0 = 1024 * 256, n1 = 144 * 512, n2 = 256 * 512;
        if (i < n0) d0[i] = f2b(s0[i]);
        else if (i < n0 + n1) d1[i - n0] = f2b(s1[i - n0]);
        else if (i < n0 + n1 + n2) d2[i - n0 - n1] = f2b(s2[i - n0 - n1]);
        return;
    }
    int row = blockIdx.x;            // b*4096 + l  (b in 0..3)
    int c = threadIdx.x;             // 0..255
    float v = x[(size_t)row * DIMC + c];
    float s1v = v, s2v = v * v;
    for (int off = 32; off; off >>= 1) {
        s1v += __shfl_xor(s1v, off, 64);
        s2v += __shfl_xor(s2v, off, 64);
    }
    __shared__ float sa[4], sb[4];
    int widx = c >> 6, lane = c & 63;
    if (lane == 0) { sa[widx] = s1v; sb[widx] = s2v; }
    __syncthreads();
    s1v = sa[0] + sa[1] + sa[2] + sa[3];
    s2v = sb[0] + sb[1] + sb[2] + sb[3];
    float mu = s1v * (1.0f / 256.0f);
    float var = s2v * (1.0f / 256.0f) - mu * mu;
    float xn = (v - mu) * rsqrtf(var + 1e-6f) * w[c] + bb[c];
    xm[(size_t)row * DIMC + c] = f2b(xn);
}

// ---------------- 128x128 LDS-tiled NT GEMM with global_load_lds staging ----------------
__global__ void __launch_bounds__(256, 4)
gemm128(const ushort_t* __restrict__ A,
        const ushort_t* __restrict__ W,
        ushort_t* __restrict__ C, int M, int N, int K) {
    __shared__ ushort_t Ash[128 * 32];
    __shared__ ushort_t Bsh[128 * 32];
    int tid = threadIdx.x;
    int lane = tid & 63, widx = tid >> 6;
    int wm = widx & 1, wn = widx >> 1;
    int l16 = lane & 15, quad = lane >> 4;
    int mblk, nblk;
    xcd_remap(2, 1, mblk, nblk);     // gy=2 for both gemm128 uses
    f32x4 acc[4][4];
    #pragma unroll
    for (int i = 0; i < 4; ++i)
        #pragma unroll
        for (int j = 0; j < 4; ++j)
            acc[i][j] = f32x4{0.0f, 0.0f, 0.0f, 0.0f};
    int srow = tid >> 2;
    int sseg = (tid & 3) * 8;
    bool jv[4];
    #pragma unroll
    for (int j = 0; j < 4; ++j) jv[j] = (nblk + wn * 64 + j * 16) < N;

    for (int k0 = 0; k0 < K; k0 += 32) {
        __syncthreads();
        #pragma unroll
        for (int q = 0; q < 2; ++q) {
            int row = q * 64 + srow;
            gload16(&A[(size_t)(mblk + row) * K + k0 + sseg], &Ash[row * 32 + sseg]);
            gload16(&W[(size_t)(nblk + row) * K + k0 + sseg], &Bsh[row * 32 + sseg]);
        }
        __syncthreads();
        short8 af[4], bf[4];
        #pragma unroll
        for (int i = 0; i < 4; ++i)
            af[i] = *(const short8*)&Ash[(wm * 64 + i * 16 + l16) * 32 + quad * 8];
        #pragma unroll
        for (int j = 0; j < 4; ++j)
            bf[j] = *(const short8*)&Bsh[(wn * 64 + j * 16 + l16) * 32 + quad * 8];
        #pragma unroll
        for (int i = 0; i < 4; ++i)
            #pragma unroll
            for (int j = 0; j < 4; ++j)
                if (jv[j])
                    acc[i][j] = __builtin_amdgcn_mfma_f32_16x16x32_bf16(af[i], bf[j], acc[i][j], 0, 0, 0);
    }
    #pragma unroll
    for (int i = 0; i < 4; ++i) {
        #pragma unroll
        for (int j = 0; j < 4; ++j) {
            if (!jv[j]) continue;
            int col = nblk + wn * 64 + j * 16 + l16;
            #pragma unroll
            for (int r = 0; r < 4; ++r) {
                int row = mblk + wm * 64 + i * 16 + quad * 4 + r;
                C[(size_t)row * N + col] = f2b(acc[i][j][r]);
            }
        }
    }
}

// ---------------- gemm128 variant: K=256, N=1024, split outputs, virtual-transposed A ----------------
// A-rows >= 16384 are read from the SINGLE-order xm with the transpose baked
// into the source-row remap (row (4+b, m) <- src b*4096 + (m&63)*64 + (m>>6)).
// Block rows never straddle the 16384 boundary (it's 128-aligned).
__global__ void __launch_bounds__(256, 4)
gemm128_split(const ushort_t* __restrict__ A,
              const ushort_t* __restrict__ W,
              ushort_t* __restrict__ outX,   // cols 0..511
              ushort_t* __restrict__ outZ) { // cols 512..1023
    const int K = 256;
    __shared__ ushort_t Ash[128 * 32];
    __shared__ ushort_t Bsh[128 * 32];
    int tid = threadIdx.x;
    int lane = tid & 63, widx = tid >> 6;
    int wm = widx & 1, wn = widx >> 1;
    int l16 = lane & 15, quad = lane >> 4;
    int mblk, nblk;
    xcd_remap(8, 3, mblk, nblk);     // gy=8
    f32x4 acc[4][4];
    #pragma unroll
    for (int i = 0; i < 4; ++i)
        #pragma unroll
        for (int j = 0; j < 4; ++j)
            acc[i][j] = f32x4{0.0f, 0.0f, 0.0f, 0.0f};
    int srow = tid >> 2;
    int sseg = (tid & 3) * 8;
    // precompute this thread's two source rows (transpose-remapped if needed)
    int srcrow[2];
    #pragma unroll
    for (int q = 0; q < 2; ++q) {
        int gr = mblk + q * 64 + srow;
        if (gr >= 16384) {
            int bq = (gr >> 12) - 4;
            int m = gr & 4095;
            srcrow[q] = bq * 4096 + ((m & 63) << 6) + (m >> 6);
        } else {
            srcrow[q] = gr;
        }
    }
    for (int k0 = 0; k0 < K; k0 += 32) {
        __syncthreads();
        #pragma unroll
        for (int q = 0; q < 2; ++q) {
            int row = q * 64 + srow;
            gload16(&A[(size_t)srcrow[q] * K + k0 + sseg], &Ash[row * 32 + sseg]);
            gload16(&W[(size_t)(nblk + row) * K + k0 + sseg], &Bsh[row * 32 + sseg]);
        }
        __syncthreads();
        short8 af[4], bf[4];
        #pragma unroll
        for (int i = 0; i < 4; ++i)
            af[i] = *(const short8*)&Ash[(wm * 64 + i * 16 + l16) * 32 + quad * 8];
        #pragma unroll
        for (int j = 0; j < 4; ++j)
            bf[j] = *(const short8*)&Bsh[(wn * 64 + j * 16 + l16) * 32 + quad * 8];
        #pragma unroll
        for (int i = 0; i < 4; ++i)
            #pragma unroll
            for (int j = 0; j < 4; ++j)
                acc[i][j] = __builtin_amdgcn_mfma_f32_16x16x32_bf16(af[i], bf[j], acc[i][j], 0, 0, 0);
    }
    #pragma unroll
    for (int i = 0; i < 4; ++i) {
        #pragma unroll
        for (int j = 0; j < 4; ++j) {
            int colg = nblk + wn * 64 + j * 16 + l16;    // tile never straddles 512
            ushort_t* dst = (colg < 512) ? outX : outZ;
            int col = colg & 511;
            #pragma unroll
            for (int r = 0; r < 4; ++r) {
                int row = mblk + wm * 64 + i * 16 + quad * 4 + r;
                dst[(size_t)row * 512 + col] = f2b(acc[i][j][r]);
            }
        }
    }
}

// ---------------- tiled conv(4)+SiLU: all-coalesced, dual output ----------------
__global__ void conv_silu_t(const ushort_t* __restrict__ xh,
                            const float* __restrict__ cw,
                            const float* __restrict__ cb,
                            ushort_t* __restrict__ xc,
                            ushort_t* __restrict__ u_T) {
    int bt0 = blockIdx.x * 64;
    int d0  = blockIdx.y * 64;
    int b   = bt0 >> 12;
    int t0  = bt0 & 4095;
    __shared__ ushort_t tin[67][66];
    __shared__ ushort_t tout[64][66];
    int tid = threadIdx.x, lane = tid & 63, widx = tid >> 6;
    for (int r = widx; r < 67; r += 4) {
        int tt = t0 - 3 + r;
        tin[r][lane] = (tt >= 0) ? xh[((size_t)bt0 - 3 + r) * 512 + d0 + lane] : (ushort_t)0;
    }
    __syncthreads();
    for (int dd = widx; dd < 64; dd += 4) {
        int d = d0 + dd;
        float acc = cb[d];
        #pragma unroll
        for (int k = 0; k < 4; ++k)
            acc += cw[d * 4 + k] * b2f(tin[lane + k][dd]);
        float s = acc / (1.0f + __expf(-acc));
        ushort_t o = f2b(s);
        u_T[((size_t)b * 512 + d) * 4096 + t0 + lane] = o;
        tout[lane][dd] = o;
    }
    __syncthreads();
    for (int r = widx; r < 64; r += 4)
        xc[((size_t)bt0 + r) * 512 + d0 + lane] = tout[r][lane];
}

// ---------------- tiled dt/w (+fused B/C pair-interleaved + state-permuted unpack) ----------------
__global__ void dt_sp_t(const ushort_t* __restrict__ xdbl,
                        const float* __restrict__ wdt,
                        const float* __restrict__ bdt,
                        const ushort_t* __restrict__ u_T,
                        ushort_t* __restrict__ dt_T,
                        ushort_t* __restrict__ w_T,
                        f32x4* __restrict__ BCfI) {
    int bt0 = blockIdx.x * 64;
    int d0  = blockIdx.y * 64;
    int b   = bt0 >> 12;
    int t0  = bt0 & 4095;
    __shared__ float din[64][17];
    int tid = threadIdx.x;
    for (int i = tid; i < 64 * 16; i += 256) {
        int r = i >> 4, k = i & 15;
        din[r][k] = b2f(xdbl[((size_t)bt0 + r) * 144 + k]);
    }
    __syncthreads();
    int lane = tid & 63, widx = tid >> 6;
    for (int dd = widx; dd < 64; dd += 4) {
        int d = d0 + dd;
        float acc = bdt[d];
        #pragma unroll
        for (int k = 0; k < 16; ++k)
            acc += din[lane][k] * wdt[d * 16 + k];
        float sp = (acc > 20.0f) ? acc : log1pf(__expf(acc));
        size_t idx = ((size_t)b * 512 + d) * 4096 + t0 + lane;
        dt_T[idx] = f2b(sp);
        float uvv = b2f(u_T[idx]);
        w_T[idx] = f2b(sp * uvv);
    }
    // fused B/C unpack, pair-interleaved + state-permuted
    if (blockIdx.y == 0) {
        for (int i = tid; i < 32 * 64; i += 256) {
            int p = i >> 6, s = i & 63;
            int sg = perm_inv(s);                 // state stored at slot s
            const ushort_t* rpe = xdbl + ((size_t)bt0 + 2 * p) * 144;
            const ushort_t* rpo = rpe + 144;
            f32x4 v;
            v.x = b2f(rpe[16 + sg]); v.y = b2f(rpe[80 + sg]);
            v.z = b2f(rpo[16 + sg]); v.w = b2f(rpo[80 + sg]);
            BCfI[((size_t)(bt0 >> 1) + p) * 64 + s] = v;
        }
    }
}

// ---------------- selective scan v20 (unchanged — 341us, ~86% of issue floor) ----------------
template<int LVL>
__device__ __forceinline__ float merge_lvl_t(float left, float right, int lane) {
    constexpr int XBIT = (LVL == 0) ? 0 : (LVL == 1) ? 1 : 3;
    bool bit = (lane >> XBIT) & 1;
    float send = bit ? left : right;
    float keep = bit ? right : left;
    float recv;
    if constexpr (LVL == 0)
        recv = __int_as_float(__builtin_amdgcn_update_dpp(
            0, __float_as_int(send), 0xB1, 0xF, 0xF, false));   // quad_perm xor1
    else if constexpr (LVL == 1)
        recv = __int_as_float(__builtin_amdgcn_update_dpp(
            0, __float_as_int(send), 0x4E, 0xF, 0xF, false));   // quad_perm xor2
    else
        recv = __int_as_float(__builtin_amdgcn_update_dpp(
            0, __float_as_int(send), 0x128, 0xF, 0xF, false));  // row_ror:8 == xor8
    return keep + recv;
}
__device__ __forceinline__ float merge_x4(float left, float right, int lane) {
    bool bit = (lane >> 2) & 1;
    float send = bit ? left : right;
    float keep = bit ? right : left;
    return keep + __shfl_xor(send, 4, 64);
}
__device__ __forceinline__ float merge16_swap(float a, float b) {
    asm volatile("s_nop 1\n\tv_permlane16_swap_b32 %0, %1" : "+v"(a), "+v"(b));
    return a + b;
}
__device__ __forceinline__ float merge32_swap(float a, float b) {
    asm volatile("s_nop 1\n\tv_permlane32_swap_b32 %0, %1" : "+v"(a), "+v"(b));
    return a + b;
}

__device__ __forceinline__ void ldg8_asm(f32x4 (&q)[8], const f32x4* bcrow, int pair0) {
    const char* g0 = (const char*)(bcrow + (size_t)pair0 * 64);
    const char* g1 = g0 + 4096;
    asm volatile(
        "global_load_dwordx4 %0, %8, off\n\t"
        "global_load_dwordx4 %1, %8, off offset:1024\n\t"
        "global_load_dwordx4 %2, %8, off offset:2048\n\t"
        "global_load_dwordx4 %3, %8, off offset:3072\n\t"
        "global_load_dwordx4 %4, %9, off\n\t"
        "global_load_dwordx4 %5, %9, off offset:1024\n\t"
        "global_load_dwordx4 %6, %9, off offset:2048\n\t"
        "global_load_dwordx4 %7, %9, off offset:3072"
        : "=&v"(q[0]), "=&v"(q[1]), "=&v"(q[2]), "=&v"(q[3]),
          "=&v"(q[4]), "=&v"(q[5]), "=&v"(q[6]), "=&v"(q[7])
        : "v"(g0), "v"(g1));
}
__device__ __forceinline__ void waitv0() {
    asm volatile("s_waitcnt vmcnt(0)" ::: "memory");
    __builtin_amdgcn_sched_barrier(0);
}

__device__ __forceinline__ float group16(const f32x4 (&qs)[8],
                                         const uint_t* __restrict__ dtw,
                                         const uint_t* __restrict__ wwp,
                                         int dwb, float a2, float& h, int lane) {
    float acc[4];
    float v16 = 0.0f;
    #pragma unroll
    for (int jj = 0; jj < 16; ++jj) {
        uint_t pd = dtw[dwb + (jj >> 1)];
        uint_t pw = wwp[dwb + (jj >> 1)];
        float sdt = __uint_as_float((jj & 1) ? (pd & 0xFFFF0000u) : (pd << 16));
        float sw  = __uint_as_float((jj & 1) ? (pw & 0xFFFF0000u) : (pw << 16));
        float bcx = (jj & 1) ? qs[jj >> 1].z : qs[jj >> 1].x;
        float bcy = (jj & 1) ? qs[jj >> 1].w : qs[jj >> 1].y;
        float dA = __builtin_amdgcn_exp2f(sdt * a2);   // raw v_exp_f32
        h = dA * h + sw * bcx;
        float v = h * bcy;
        const int dest = (jj == 15) ? 4 : __builtin_ctz(~(unsigned)jj);
        if (0 < dest) v = merge_lvl_t<0>(acc[0], v, lane);
        if (1 < dest) v = merge_lvl_t<1>(acc[1], v, lane);
        if (2 < dest) v = merge_lvl_t<2>(acc[2], v, lane);
        if (3 < dest) v = merge16_swap(acc[3], v);     // xor16 (VALU)
        if (jj == 15) v16 = v;
        else acc[dest] = v;
    }
    return v16;
}

__global__ void __launch_bounds__(256, 4)
scan20(const ushort_t* __restrict__ dt_T,
       ushort_t* uT_ysT,
       const ushort_t* __restrict__ w_T,
       const f32x4* __restrict__ BCfI,
       const float* __restrict__ Alog,
       const float* __restrict__ Dp) {
    int tid = threadIdx.x;
    int lane = tid & 63, widx = tid >> 6;
    int blk = blockIdx.x;
    int wid = (blk & 7) * 512 + (blk >> 3) * 4 + widx;   // b = blk&7 (XCD affinity)
    int b = wid >> 9, d = wid & 511;
    int pinv = perm_inv(lane);
    float a2 = -__expf(Alog[d * 64 + pinv]) * 1.442695041f;
    float Dd = Dp[d];
    float h = 0.0f;
    size_t rowT = ((size_t)b * 512 + d) * 4096;
    uint_t rowTu = __builtin_amdgcn_readfirstlane((uint_t)rowT);
    const uint_t* dtw = (const uint_t*)(dt_T + rowTu);
    const uint_t* wwp = (const uint_t*)(w_T + rowTu);
    const f32x4* bcrow = BCfI + ((size_t)b * 2048) * 64 + lane;

    f32x4 qA[8], qB[8];
    ldg8_asm(qA, bcrow, 0);                      // prolog issue (group 0)
    float uv = b2f(uT_ysT[rowT + pinv]);         // prolog u (slab 0)
    ushort_t ypend = 0;
    #pragma unroll 1
    for (int sl = 0; sl < 64; ++sl) {
        int t0 = sl * 64;
        int dwb = t0 >> 1;
        // g0: wait qA -> issue qB -> deferred y store -> compute qA
        waitv0();
        ldg8_asm(qB, bcrow, dwb + 8);
        if (sl) uT_ysT[rowT + t0 - 64 + pinv] = ypend;
        float s4 = group16(qA, dtw, wwp, dwb, a2, h, lane);
        // g1
        waitv0();
        ldg8_asm(qA, bcrow, dwb + 16);
        float s5 = merge32_swap(s4, group16(qB, dtw, wwp, dwb + 8, a2, h, lane)); // lvl4: xor32
        // g2
        waitv0();
        ldg8_asm(qB, bcrow, dwb + 24);
        s4 = group16(qA, dtw, wwp, dwb + 16, a2, h, lane);
        // g3: prefetch next slab's group 0 + next slab's u
        waitv0();
        float uvn = 0.0f;
        if (sl < 63) {
            ldg8_asm(qA, bcrow, dwb + 32);
            uvn = b2f(uT_ysT[rowT + t0 + 64 + pinv]);
        }
        float m = merge32_swap(s4, group16(qB, dtw, wwp, dwb + 24, a2, h, lane)); // lvl4
        float yfin = merge_x4(s5, m, lane);                                       // lvl5: xor4
        ypend = f2b(yfin + uv * Dd);
        uv = uvn;
    }
    uT_ysT[rowT + (LSEQ - 64) + pinv] = ypend;
}

// ---------------- gate + transpose: ys[bt,d] = ysT[b,d,t] * silu(z[bt,d]) ----------------
__global__ void gate_t(const ushort_t* __restrict__ ysT,
                       const ushort_t* __restrict__ zb,
                       ushort_t* __restrict__ ys) {
    int bt0 = blockIdx.x * 64;
    int d0  = blockIdx.y * 64;
    int b   = bt0 >> 12;
    int t0  = bt0 & 4095;
    __shared__ ushort_t tile[64][66];
    int tid = threadIdx.x, lane = tid & 63, widx = tid >> 6;
    for (int dd = widx; dd < 64; dd += 4)
        tile[dd][lane] = ysT[((size_t)b * 512 + d0 + dd) * 4096 + t0 + lane];
    __syncthreads();
    for (int r = widx; r < 64; r += 4) {
        float zv = b2f(zb[((size_t)bt0 + r) * 512 + d0 + lane]);
        float yv = b2f(tile[lane][r]);
        float g = zv / (1.0f + __expf(-zv));
        ys[((size_t)bt0 + r) * 512 + d0 + lane] = f2b(yv * g);
    }
}

// ---------------- final LN + transpose-combine + residual (fp32 out) ----------------
__global__ void final_ln_add(const ushort_t* __restrict__ outm,
                             const float* __restrict__ x,
                             const float* __restrict__ w,
                             const float* __restrict__ bb,
                             float* __restrict__ out) {
    int row = blockIdx.x;
    int c = threadIdx.x;
    int b = row >> 12, l = row & 4095, i = l >> 6, j = l & 63;
    size_t rA = ((size_t)b * LSEQ + l) * DIMC;
    size_t rB = ((size_t)(4 + b) * LSEQ + (j * 64 + i)) * DIMC;
    float va = b2f(outm[rA + c]);
    float vb = b2f(outm[rB + c]);
    float s1 = va, s2 = va * va, s3 = vb, s4 = vb * vb;
    for (int off = 32; off; off >>= 1) {
        s1 += __shfl_xor(s1, off, 64);
        s2 += __shfl_xor(s2, off, 64);
        s3 += __shfl_xor(s3, off, 64);
        s4 += __shfl_xor(s4, off, 64);
    }
    __shared__ float sm[4][4];
    int widx = c >> 6, lane = c & 63;
    if (lane == 0) { sm[widx][0] = s1; sm[widx][1] = s2; sm[widx][2] = s3; sm[widx][3] = s4; }
    __syncthreads();
    s1 = sm[0][0] + sm[1][0] + sm[2][0] + sm[3][0];
    s2 = sm[0][1] + sm[1][1] + sm[2][1] + sm[3][1];
    s3 = sm[0][2] + sm[1][2] + sm[2][2] + sm[3][2];
    s4 = sm[0][3] + sm[1][3] + sm[2][3] + sm[3][3];
    float muA = s1 * (1.0f / 256.0f), varA = s2 * (1.0f / 256.0f) - muA * muA;
    float muB = s3 * (1.0f / 256.0f), varB = s4 * (1.0f / 256.0f) - muB * muB;
    float lw = w[c], lb = bb[c];
    float ya = (va - muA) * rsqrtf(varA + 1e-6f) * lw + lb;
    float yb = (vb - muB) * rsqrtf(varB + 1e-6f) * lw + lb;
    float xo = x[(size_t)row * DIMC + c];
    out[(size_t)row * DIMC + c] = xo + ya + yb;
}

extern "C" void kernel_launch(void* const* d_in, const int* in_sizes, int n_in,
                              void* d_out, int out_size, void* d_ws, size_t ws_size,
                              hipStream_t stream) {
    const float* x      = (const float*)d_in[0];
    const float* ln1_w  = (const float*)d_in[1];
    const float* ln1_b  = (const float*)d_in[2];
    const float* ln2_w  = (const float*)d_in[3];
    const float* ln2_b  = (const float*)d_in[4];
    const float* W_in   = (const float*)d_in[5];
    const float* conv_w = (const float*)d_in[6];
    const float* conv_b = (const float*)d_in[7];
    const float* W_x    = (const float*)d_in[8];
    const float* W_dt   = (const float*)d_in[9];
    const float* b_dt   = (const float*)d_in[10];
    const float* A_log  = (const float*)d_in[11];
    const float* D_par  = (const float*)d_in[12];
    const float* W_out  = (const float*)d_in[13];
    float* out = (float*)d_out;

    // ---- workspace (~169 MB) ----
    char* ws = (char*)d_ws;
    size_t off = 0;
    ushort_t* wb_in  = (ushort_t*)(ws + off); off += (size_t)1024 * 256 * 2;
    ushort_t* wb_x   = (ushort_t*)(ws + off); off += (size_t)144 * 512 * 2;
    ushort_t* wb_out = (ushort_t*)(ws + off); off += (size_t)256 * 512 * 2;
    const size_t R0 = (size_t)MROWS * DIMC * 2;
    const size_t R1 = (size_t)MROWS * 512 * 2;
    ushort_t* r0 = (ushort_t*)(ws + off); off += R0;   // xm -> xdbl -> outm
    ushort_t* r1 = (ushort_t*)(ws + off); off += R1;   // xhalf -> dt_T
    ushort_t* r2 = (ushort_t*)(ws + off); off += R1;   // z
    ushort_t* r3 = (ushort_t*)(ws + off); off += R1;   // xc -> w_T -> ys
    ushort_t* r4 = (ushort_t*)(ws + off); off += R1;   // u_T -> ysT (in place)
    f32x4*    BCfI = (f32x4*)(ws + off);  off += (size_t)MROWS * 64 * 8;  // 16.8 MB

    ushort_t* xm    = r0;
    ushort_t* xdbl  = r0;
    ushort_t* outm  = r0;
    ushort_t* xhalf = r1;
    ushort_t* dt_T  = r1;
    ushort_t* zb    = r2;
    ushort_t* xc    = r3;
    ushort_t* w_T   = r3;
    ushort_t* ys    = r3;
    ushort_t* u_T   = r4;

    // A. merged: weight cvt + LayerNorm + single-order xm (one launch)
    const int ncvt = 1024 * 256 + 144 * 512 + 256 * 512;
    const int cvtblk = (ncvt + 255) / 256;
    hipLaunchKernelGGL(cvt_ln1, dim3(16384 + cvtblk), dim3(256), 0, stream,
                       x, ln1_w, ln1_b, xm, W_in, wb_in, W_x, wb_x, W_out, wb_out);
    // B. one launch: cols<512 -> xhalf, cols>=512 -> zb   (XCD-swizzled,
    //    virtual-transposed A for rows >= 16384)
    hipLaunchKernelGGL(gemm128_split, dim3(MROWS / 128, 8), dim3(256), 0, stream,
                       xm, wb_in, xhalf, zb);
    // C. tiled conv + SiLU: xhalf -> xc[bt,d] + u_T[b,d,t]
    hipLaunchKernelGGL(conv_silu_t, dim3(MROWS / 64, 8), dim3(256), 0, stream,
                       xhalf, conv_w, conv_b, xc, u_T);
    // D. x_dbl = xc @ W_x^T   (N=144, K=512)   (XCD-swizzled)
    hipLaunchKernelGGL(gemm128, dim3(MROWS / 128, 2), dim3(256), 0, stream,
                       xc, wb_x, xdbl, MROWS, 144, 512);
    // E. dt/w (+ pair-interleaved, state-permuted B/C unpack)
    hipLaunchKernelGGL(dt_sp_t, dim3(MROWS / 64, 8), dim3(256), 0, stream,
                       xdbl, W_dt, b_dt, u_T, dt_T, w_T, BCfI);
    // F. selective scan v20: asm-pinned pipelined direct-global
    hipLaunchKernelGGL(scan20, dim3(BS2 * 512 / 4), dim3(256), 0, stream,
                       dt_T, u_T, w_T, BCfI, A_log, D_par);
    // G. gate + transpose: ys[bt,d] = ysT * silu(z)
    hipLaunchKernelGGL(gate_t, dim3(MROWS / 64, 8), dim3(256), 0, stream,
                       u_T, zb, ys);
    // H. outm = ys @ W_out^T   (N=256, K=512)   (XCD-swizzled)
    hipLaunchKernelGGL(gemm128, dim3(MROWS / 128, 2), dim3(256), 0, stream,
                       ys, wb_out, outm, MROWS, 256, 512);
    // I. final LN + transpose combine + residual (fp32 out)
    hipLaunchKernelGGL(final_ln_add, dim3(4 * LSEQ), dim3(256), 0, stream,
                       outm, x, ln2_w, ln2_b, out);
}

// Round 12
// 610.652 us; speedup vs baseline: 1.0124x; 1.0124x over previous
//
#include <hip/hip_runtime.h>
#include <hip/hip_bf16.h>

typedef unsigned short ushort_t;
typedef unsigned int uint_t;
typedef __attribute__((ext_vector_type(8))) short short8;
typedef __attribute__((ext_vector_type(4))) float f32x4;

#define DIMC 256
#define D_INNER 512
#define D_STATE 64
#define DT_RANK 16
#define LSEQ 4096
#define BS2 8            // 2*BS batches through mamba
#define MROWS (BS2*LSEQ) // 32768

// lane-bit permutation for the scan merge tree (v15-verified):
// t-bit b -> lane-xor bit pi(b): pi = {0,1,3,4,5,2}
__device__ __forceinline__ int perm_inv(int p) {
    return (p & 3) | ((p & 0x38) >> 1) | ((p & 4) << 3);
}

__device__ __forceinline__ float b2f(ushort_t u) {
    union { uint_t i; float f; } v; v.i = ((uint_t)u) << 16; return v.f;
}
__device__ __forceinline__ ushort_t f2b(float f) {
    union { float f; uint_t i; } v; v.f = f;
    uint_t r = v.i + 0x7FFFu + ((v.i >> 16) & 1u);   // RNE
    return (ushort_t)(r >> 16);
}

// async global->LDS 16B per lane (HW: wave-uniform LDS base + lane*16)
typedef __attribute__((address_space(1))) const unsigned int gas_u32;
typedef __attribute__((address_space(3))) unsigned int las_u32;
__device__ __forceinline__ void gload16(const void* g, void* l) {
    __builtin_amdgcn_global_load_lds((gas_u32*)g, (las_u32*)l, 16, 0, 0);
}

// XCD-aware block remap for GEMMs [v17/v18 measured: ~12us tail gain — kept]
__device__ __forceinline__ void xcd_remap(int gy, int ybits, int& mblk, int& nblk) {
    int idl = blockIdx.x + gridDim.x * blockIdx.y;
    int xcdc = idl & 7;
    int rest = idl >> 3;
    int y = rest & (gy - 1);
    int xhi = rest >> ybits;
    mblk = (xhi * 8 + xcdc) * 128;
    nblk = y * 128;
}

// ---------------- merged: LN1+dual-order xm (blocks 0..16383) + weight cvt (rest) ----------------
// v21's single-order xm + gather-transposed A regressed (−7us): the remapped
// rows are 64 apart -> 16 scattered 64B segments per staged wave, executed 8x
// (per k0) vs the write executed once. Dual-order materialization restored.
__global__ void cvt_ln1(const float* __restrict__ x,
                        const float* __restrict__ w,
                        const float* __restrict__ bb,
                        ushort_t* __restrict__ xm,
                        const float* __restrict__ s0, ushort_t* __restrict__ d0,
                        const float* __restrict__ s1, ushort_t* __restrict__ d1,
                        const float* __restrict__ s2, ushort_t* __restrict__ d2) {
    if (blockIdx.x >= 16384) {
        int i = (blockIdx.x - 16384) * 256 + threadIdx.x;
        const int n0 = 1024 * 256, n1 = 144 * 512, n2 = 256 * 512;
        if (i < n0) d0[i] = f2b(s0[i]);
        else if (i < n0 + n1) d1[i - n0] = f2b(s1[i - n0]);
        else if (i < n0 + n1 + n2) d2[i - n0 - n1] = f2b(s2[i - n0 - n1]);
        return;
    }
    int row = blockIdx.x;            // b*4096 + l  (b in 0..3)
    int c = threadIdx.x;             // 0..255
    float v = x[(size_t)row * DIMC + c];
    float s1v = v, s2v = v * v;
    for (int off = 32; off; off >>= 1) {
        s1v += __shfl_xor(s1v, off, 64);
        s2v += __shfl_xor(s2v, off, 64);
    }
    __shared__ float sa[4], sb[4];
    int widx = c >> 6, lane = c & 63;
    if (lane == 0) { sa[widx] = s1v; sb[widx] = s2v; }
    __syncthreads();
    s1v = sa[0] + sa[1] + sa[2] + sa[3];
    s2v = sb[0] + sb[1] + sb[2] + sb[3];
    float mu = s1v * (1.0f / 256.0f);
    float var = s2v * (1.0f / 256.0f) - mu * mu;
    float xn = (v - mu) * rsqrtf(var + 1e-6f) * w[c] + bb[c];
    ushort_t o = f2b(xn);
    int b = row >> 12, l = row & 4095, i = l >> 6, j = l & 63;
    xm[((size_t)b * LSEQ + l) * DIMC + c] = o;
    xm[((size_t)(4 + b) * LSEQ + (j * 64 + i)) * DIMC + c] = o;
}

// ---------------- 128x128 LDS-tiled NT GEMM with global_load_lds staging ----------------
__global__ void __launch_bounds__(256, 4)
gemm128(const ushort_t* __restrict__ A,
        const ushort_t* __restrict__ W,
        ushort_t* __restrict__ C, int M, int N, int K) {
    __shared__ ushort_t Ash[128 * 32];
    __shared__ ushort_t Bsh[128 * 32];
    int tid = threadIdx.x;
    int lane = tid & 63, widx = tid >> 6;
    int wm = widx & 1, wn = widx >> 1;
    int l16 = lane & 15, quad = lane >> 4;
    int mblk, nblk;
    xcd_remap(2, 1, mblk, nblk);     // gy=2 for both gemm128 uses
    f32x4 acc[4][4];
    #pragma unroll
    for (int i = 0; i < 4; ++i)
        #pragma unroll
        for (int j = 0; j < 4; ++j)
            acc[i][j] = f32x4{0.0f, 0.0f, 0.0f, 0.0f};
    int srow = tid >> 2;
    int sseg = (tid & 3) * 8;
    bool jv[4];
    #pragma unroll
    for (int j = 0; j < 4; ++j) jv[j] = (nblk + wn * 64 + j * 16) < N;

    for (int k0 = 0; k0 < K; k0 += 32) {
        __syncthreads();
        #pragma unroll
        for (int q = 0; q < 2; ++q) {
            int row = q * 64 + srow;
            gload16(&A[(size_t)(mblk + row) * K + k0 + sseg], &Ash[row * 32 + sseg]);
            gload16(&W[(size_t)(nblk + row) * K + k0 + sseg], &Bsh[row * 32 + sseg]);
        }
        __syncthreads();
        short8 af[4], bf[4];
        #pragma unroll
        for (int i = 0; i < 4; ++i)
            af[i] = *(const short8*)&Ash[(wm * 64 + i * 16 + l16) * 32 + quad * 8];
        #pragma unroll
        for (int j = 0; j < 4; ++j)
            bf[j] = *(const short8*)&Bsh[(wn * 64 + j * 16 + l16) * 32 + quad * 8];
        #pragma unroll
        for (int i = 0; i < 4; ++i)
            #pragma unroll
            for (int j = 0; j < 4; ++j)
                if (jv[j])
                    acc[i][j] = __builtin_amdgcn_mfma_f32_16x16x32_bf16(af[i], bf[j], acc[i][j], 0, 0, 0);
    }
    #pragma unroll
    for (int i = 0; i < 4; ++i) {
        #pragma unroll
        for (int j = 0; j < 4; ++j) {
            if (!jv[j]) continue;
            int col = nblk + wn * 64 + j * 16 + l16;
            #pragma unroll
            for (int r = 0; r < 4; ++r) {
                int row = mblk + wm * 64 + i * 16 + quad * 4 + r;
                C[(size_t)row * N + col] = f2b(acc[i][j][r]);
            }
        }
    }
}

// ---------------- gemm128 variant: K=256, N=1024, split outputs at col 512 ----------------
__global__ void __launch_bounds__(256, 4)
gemm128_split(const ushort_t* __restrict__ A,
              const ushort_t* __restrict__ W,
              ushort_t* __restrict__ outX,   // cols 0..511
              ushort_t* __restrict__ outZ) { // cols 512..1023
    const int K = 256;
    __shared__ ushort_t Ash[128 * 32];
    __shared__ ushort_t Bsh[128 * 32];
    int tid = threadIdx.x;
    int lane = tid & 63, widx = tid >> 6;
    int wm = widx & 1, wn = widx >> 1;
    int l16 = lane & 15, quad = lane >> 4;
    int mblk, nblk;
    xcd_remap(8, 3, mblk, nblk);     // gy=8
    f32x4 acc[4][4];
    #pragma unroll
    for (int i = 0; i < 4; ++i)
        #pragma unroll
        for (int j = 0; j < 4; ++j)
            acc[i][j] = f32x4{0.0f, 0.0f, 0.0f, 0.0f};
    int srow = tid >> 2;
    int sseg = (tid & 3) * 8;
    for (int k0 = 0; k0 < K; k0 += 32) {
        __syncthreads();
        #pragma unroll
        for (int q = 0; q < 2; ++q) {
            int row = q * 64 + srow;
            gload16(&A[(size_t)(mblk + row) * K + k0 + sseg], &Ash[row * 32 + sseg]);
            gload16(&W[(size_t)(nblk + row) * K + k0 + sseg], &Bsh[row * 32 + sseg]);
        }
        __syncthreads();
        short8 af[4], bf[4];
        #pragma unroll
        for (int i = 0; i < 4; ++i)
            af[i] = *(const short8*)&Ash[(wm * 64 + i * 16 + l16) * 32 + quad * 8];
        #pragma unroll
        for (int j = 0; j < 4; ++j)
            bf[j] = *(const short8*)&Bsh[(wn * 64 + j * 16 + l16) * 32 + quad * 8];
        #pragma unroll
        for (int i = 0; i < 4; ++i)
            #pragma unroll
            for (int j = 0; j < 4; ++j)
                acc[i][j] = __builtin_amdgcn_mfma_f32_16x16x32_bf16(af[i], bf[j], acc[i][j], 0, 0, 0);
    }
    #pragma unroll
    for (int i = 0; i < 4; ++i) {
        #pragma unroll
        for (int j = 0; j < 4; ++j) {
            int colg = nblk + wn * 64 + j * 16 + l16;    // tile never straddles 512
            ushort_t* dst = (colg < 512) ? outX : outZ;
            int col = colg & 511;
            #pragma unroll
            for (int r = 0; r < 4; ++r) {
                int row = mblk + wm * 64 + i * 16 + quad * 4 + r;
                dst[(size_t)row * 512 + col] = f2b(acc[i][j][r]);
            }
        }
    }
}

// ---------------- tiled conv(4)+SiLU: all-coalesced, dual output ----------------
__global__ void conv_silu_t(const ushort_t* __restrict__ xh,
                            const float* __restrict__ cw,
                            const float* __restrict__ cb,
                            ushort_t* __restrict__ xc,
                            ushort_t* __restrict__ u_T) {
    int bt0 = blockIdx.x * 64;
    int d0  = blockIdx.y * 64;
    int b   = bt0 >> 12;
    int t0  = bt0 & 4095;
    __shared__ ushort_t tin[67][66];
    __shared__ ushort_t tout[64][66];
    int tid = threadIdx.x, lane = tid & 63, widx = tid >> 6;
    for (int r = widx; r < 67; r += 4) {
        int tt = t0 - 3 + r;
        tin[r][lane] = (tt >= 0) ? xh[((size_t)bt0 - 3 + r) * 512 + d0 + lane] : (ushort_t)0;
    }
    __syncthreads();
    for (int dd = widx; dd < 64; dd += 4) {
        int d = d0 + dd;
        float acc = cb[d];
        #pragma unroll
        for (int k = 0; k < 4; ++k)
            acc += cw[d * 4 + k] * b2f(tin[lane + k][dd]);
        float s = acc / (1.0f + __expf(-acc));
        ushort_t o = f2b(s);
        u_T[((size_t)b * 512 + d) * 4096 + t0 + lane] = o;
        tout[lane][dd] = o;
    }
    __syncthreads();
    for (int r = widx; r < 64; r += 4)
        xc[((size_t)bt0 + r) * 512 + d0 + lane] = tout[r][lane];
}

// ---------------- tiled dt/w (+fused B/C pair-interleaved + state-permuted unpack) ----------------
__global__ void dt_sp_t(const ushort_t* __restrict__ xdbl,
                        const float* __restrict__ wdt,
                        const float* __restrict__ bdt,
                        const ushort_t* __restrict__ u_T,
                        ushort_t* __restrict__ dt_T,
                        ushort_t* __restrict__ w_T,
                        f32x4* __restrict__ BCfI) {
    int bt0 = blockIdx.x * 64;
    int d0  = blockIdx.y * 64;
    int b   = bt0 >> 12;
    int t0  = bt0 & 4095;
    __shared__ float din[64][17];
    int tid = threadIdx.x;
    for (int i = tid; i < 64 * 16; i += 256) {
        int r = i >> 4, k = i & 15;
        din[r][k] = b2f(xdbl[((size_t)bt0 + r) * 144 + k]);
    }
    __syncthreads();
    int lane = tid & 63, widx = tid >> 6;
    for (int dd = widx; dd < 64; dd += 4) {
        int d = d0 + dd;
        float acc = bdt[d];
        #pragma unroll
        for (int k = 0; k < 16; ++k)
            acc += din[lane][k] * wdt[d * 16 + k];
        float sp = (acc > 20.0f) ? acc : log1pf(__expf(acc));
        size_t idx = ((size_t)b * 512 + d) * 4096 + t0 + lane;
        dt_T[idx] = f2b(sp);
        float uvv = b2f(u_T[idx]);
        w_T[idx] = f2b(sp * uvv);
    }
    // fused B/C unpack, pair-interleaved + state-permuted
    if (blockIdx.y == 0) {
        for (int i = tid; i < 32 * 64; i += 256) {
            int p = i >> 6, s = i & 63;
            int sg = perm_inv(s);                 // state stored at slot s
            const ushort_t* rpe = xdbl + ((size_t)bt0 + 2 * p) * 144;
            const ushort_t* rpo = rpe + 144;
            f32x4 v;
            v.x = b2f(rpe[16 + sg]); v.y = b2f(rpe[80 + sg]);
            v.z = b2f(rpo[16 + sg]); v.w = b2f(rpo[80 + sg]);
            BCfI[((size_t)(bt0 >> 1) + p) * 64 + s] = v;
        }
    }
}

// ---------------- selective scan v20 (best measured: 341us, ~86% of issue floor) ----------------
template<int LVL>
__device__ __forceinline__ float merge_lvl_t(float left, float right, int lane) {
    constexpr int XBIT = (LVL == 0) ? 0 : (LVL == 1) ? 1 : 3;
    bool bit = (lane >> XBIT) & 1;
    float send = bit ? left : right;
    float keep = bit ? right : left;
    float recv;
    if constexpr (LVL == 0)
        recv = __int_as_float(__builtin_amdgcn_update_dpp(
            0, __float_as_int(send), 0xB1, 0xF, 0xF, false));   // quad_perm xor1
    else if constexpr (LVL == 1)
        recv = __int_as_float(__builtin_amdgcn_update_dpp(
            0, __float_as_int(send), 0x4E, 0xF, 0xF, false));   // quad_perm xor2
    else
        recv = __int_as_float(__builtin_amdgcn_update_dpp(
            0, __float_as_int(send), 0x128, 0xF, 0xF, false));  // row_ror:8 == xor8
    return keep + recv;
}
__device__ __forceinline__ float merge_x4(float left, float right, int lane) {
    bool bit = (lane >> 2) & 1;
    float send = bit ? left : right;
    float keep = bit ? right : left;
    return keep + __shfl_xor(send, 4, 64);
}
__device__ __forceinline__ float merge16_swap(float a, float b) {
    asm volatile("s_nop 1\n\tv_permlane16_swap_b32 %0, %1" : "+v"(a), "+v"(b));
    return a + b;
}
__device__ __forceinline__ float merge32_swap(float a, float b) {
    asm volatile("s_nop 1\n\tv_permlane32_swap_b32 %0, %1" : "+v"(a), "+v"(b));
    return a + b;
}

__device__ __forceinline__ void ldg8_asm(f32x4 (&q)[8], const f32x4* bcrow, int pair0) {
    const char* g0 = (const char*)(bcrow + (size_t)pair0 * 64);
    const char* g1 = g0 + 4096;
    asm volatile(
        "global_load_dwordx4 %0, %8, off\n\t"
        "global_load_dwordx4 %1, %8, off offset:1024\n\t"
        "global_load_dwordx4 %2, %8, off offset:2048\n\t"
        "global_load_dwordx4 %3, %8, off offset:3072\n\t"
        "global_load_dwordx4 %4, %9, off\n\t"
        "global_load_dwordx4 %5, %9, off offset:1024\n\t"
        "global_load_dwordx4 %6, %9, off offset:2048\n\t"
        "global_load_dwordx4 %7, %9, off offset:3072"
        : "=&v"(q[0]), "=&v"(q[1]), "=&v"(q[2]), "=&v"(q[3]),
          "=&v"(q[4]), "=&v"(q[5]), "=&v"(q[6]), "=&v"(q[7])
        : "v"(g0), "v"(g1));
}
__device__ __forceinline__ void waitv0() {
    asm volatile("s_waitcnt vmcnt(0)" ::: "memory");
    __builtin_amdgcn_sched_barrier(0);
}

__device__ __forceinline__ float group16(const f32x4 (&qs)[8],
                                         const uint_t* __restrict__ dtw,
                                         const uint_t* __restrict__ wwp,
                                         int dwb, float a2, float& h, int lane) {
    float acc[4];
    float v16 = 0.0f;
    #pragma unroll
    for (int jj = 0; jj < 16; ++jj) {
        uint_t pd = dtw[dwb + (jj >> 1)];
        uint_t pw = wwp[dwb + (jj >> 1)];
        float sdt = __uint_as_float((jj & 1) ? (pd & 0xFFFF0000u) : (pd << 16));
        float sw  = __uint_as_float((jj & 1) ? (pw & 0xFFFF0000u) : (pw << 16));
        float bcx = (jj & 1) ? qs[jj >> 1].z : qs[jj >> 1].x;
        float bcy = (jj & 1) ? qs[jj >> 1].w : qs[jj >> 1].y;
        float dA = __builtin_amdgcn_exp2f(sdt * a2);   // raw v_exp_f32
        h = dA * h + sw * bcx;
        float v = h * bcy;
        const int dest = (jj == 15) ? 4 : __builtin_ctz(~(unsigned)jj);
        if (0 < dest) v = merge_lvl_t<0>(acc[0], v, lane);
        if (1 < dest) v = merge_lvl_t<1>(acc[1], v, lane);
        if (2 < dest) v = merge_lvl_t<2>(acc[2], v, lane);
        if (3 < dest) v = merge16_swap(acc[3], v);     // xor16 (VALU)
        if (jj == 15) v16 = v;
        else acc[dest] = v;
    }
    return v16;
}

__global__ void __launch_bounds__(256, 4)
scan20(const ushort_t* __restrict__ dt_T,
       ushort_t* uT_ysT,
       const ushort_t* __restrict__ w_T,
       const f32x4* __restrict__ BCfI,
       const float* __restrict__ Alog,
       const float* __restrict__ Dp) {
    int tid = threadIdx.x;
    int lane = tid & 63, widx = tid >> 6;
    int blk = blockIdx.x;
    int wid = (blk & 7) * 512 + (blk >> 3) * 4 + widx;   // b = blk&7 (XCD affinity)
    int b = wid >> 9, d = wid & 511;
    int pinv = perm_inv(lane);
    float a2 = -__expf(Alog[d * 64 + pinv]) * 1.442695041f;
    float Dd = Dp[d];
    float h = 0.0f;
    size_t rowT = ((size_t)b * 512 + d) * 4096;
    uint_t rowTu = __builtin_amdgcn_readfirstlane((uint_t)rowT);
    const uint_t* dtw = (const uint_t*)(dt_T + rowTu);
    const uint_t* wwp = (const uint_t*)(w_T + rowTu);
    const f32x4* bcrow = BCfI + ((size_t)b * 2048) * 64 + lane;

    f32x4 qA[8], qB[8];
    ldg8_asm(qA, bcrow, 0);                      // prolog issue (group 0)
    float uv = b2f(uT_ysT[rowT + pinv]);         // prolog u (slab 0)
    ushort_t ypend = 0;
    #pragma unroll 1
    for (int sl = 0; sl < 64; ++sl) {
        int t0 = sl * 64;
        int dwb = t0 >> 1;
        // g0: wait qA -> issue qB -> deferred y store -> compute qA
        waitv0();
        ldg8_asm(qB, bcrow, dwb + 8);
        if (sl) uT_ysT[rowT + t0 - 64 + pinv] = ypend;
        float s4 = group16(qA, dtw, wwp, dwb, a2, h, lane);
        // g1
        waitv0();
        ldg8_asm(qA, bcrow, dwb + 16);
        float s5 = merge32_swap(s4, group16(qB, dtw, wwp, dwb + 8, a2, h, lane)); // lvl4: xor32
        // g2
        waitv0();
        ldg8_asm(qB, bcrow, dwb + 24);
        s4 = group16(qA, dtw, wwp, dwb + 16, a2, h, lane);
        // g3: prefetch next slab's group 0 + next slab's u
        waitv0();
        float uvn = 0.0f;
        if (sl < 63) {
            ldg8_asm(qA, bcrow, dwb + 32);
            uvn = b2f(uT_ysT[rowT + t0 + 64 + pinv]);
        }
        float m = merge32_swap(s4, group16(qB, dtw, wwp, dwb + 24, a2, h, lane)); // lvl4
        float yfin = merge_x4(s5, m, lane);                                       // lvl5: xor4
        ypend = f2b(yfin + uv * Dd);
        uv = uvn;
    }
    uT_ysT[rowT + (LSEQ - 64) + pinv] = ypend;
}

// ---------------- gate + transpose: ys[bt,d] = ysT[b,d,t] * silu(z[bt,d]) ----------------
__global__ void gate_t(const ushort_t* __restrict__ ysT,
                       const ushort_t* __restrict__ zb,
                       ushort_t* __restrict__ ys) {
    int bt0 = blockIdx.x * 64;
    int d0  = blockIdx.y * 64;
    int b   = bt0 >> 12;
    int t0  = bt0 & 4095;
    __shared__ ushort_t tile[64][66];
    int tid = threadIdx.x, lane = tid & 63, widx = tid >> 6;
    for (int dd = widx; dd < 64; dd += 4)
        tile[dd][lane] = ysT[((size_t)b * 512 + d0 + dd) * 4096 + t0 + lane];
    __syncthreads();
    for (int r = widx; r < 64; r += 4) {
        float zv = b2f(zb[((size_t)bt0 + r) * 512 + d0 + lane]);
        float yv = b2f(tile[lane][r]);
        float g = zv / (1.0f + __expf(-zv));
        ys[((size_t)bt0 + r) * 512 + d0 + lane] = f2b(yv * g);
    }
}

// ---------------- final LN + transpose-combine + residual (fp32 out) ----------------
__global__ void final_ln_add(const ushort_t* __restrict__ outm,
                             const float* __restrict__ x,
                             const float* __restrict__ w,
                             const float* __restrict__ bb,
                             float* __restrict__ out) {
    int row = blockIdx.x;
    int c = threadIdx.x;
    int b = row >> 12, l = row & 4095, i = l >> 6, j = l & 63;
    size_t rA = ((size_t)b * LSEQ + l) * DIMC;
    size_t rB = ((size_t)(4 + b) * LSEQ + (j * 64 + i)) * DIMC;
    float va = b2f(outm[rA + c]);
    float vb = b2f(outm[rB + c]);
    float s1 = va, s2 = va * va, s3 = vb, s4 = vb * vb;
    for (int off = 32; off; off >>= 1) {
        s1 += __shfl_xor(s1, off, 64);
        s2 += __shfl_xor(s2, off, 64);
        s3 += __shfl_xor(s3, off, 64);
        s4 += __shfl_xor(s4, off, 64);
    }
    __shared__ float sm[4][4];
    int widx = c >> 6, lane = c & 63;
    if (lane == 0) { sm[widx][0] = s1; sm[widx][1] = s2; sm[widx][2] = s3; sm[widx][3] = s4; }
    __syncthreads();
    s1 = sm[0][0] + sm[1][0] + sm[2][0] + sm[3][0];
    s2 = sm[0][1] + sm[1][1] + sm[2][1] + sm[3][1];
    s3 = sm[0][2] + sm[1][2] + sm[2][2] + sm[3][2];
    s4 = sm[0][3] + sm[1][3] + sm[2][3] + sm[3][3];
    float muA = s1 * (1.0f / 256.0f), varA = s2 * (1.0f / 256.0f) - muA * muA;
    float muB = s3 * (1.0f / 256.0f), varB = s4 * (1.0f / 256.0f) - muB * muB;
    float lw = w[c], lb = bb[c];
    float ya = (va - muA) * rsqrtf(varA + 1e-6f) * lw + lb;
    float yb = (vb - muB) * rsqrtf(varB + 1e-6f) * lw + lb;
    float xo = x[(size_t)row * DIMC + c];
    out[(size_t)row * DIMC + c] = xo + ya + yb;
}

extern "C" void kernel_launch(void* const* d_in, const int* in_sizes, int n_in,
                              void* d_out, int out_size, void* d_ws, size_t ws_size,
                              hipStream_t stream) {
    const float* x      = (const float*)d_in[0];
    const float* ln1_w  = (const float*)d_in[1];
    const float* ln1_b  = (const float*)d_in[2];
    const float* ln2_w  = (const float*)d_in[3];
    const float* ln2_b  = (const float*)d_in[4];
    const float* W_in   = (const float*)d_in[5];
    const float* conv_w = (const float*)d_in[6];
    const float* conv_b = (const float*)d_in[7];
    const float* W_x    = (const float*)d_in[8];
    const float* W_dt   = (const float*)d_in[9];
    const float* b_dt   = (const float*)d_in[10];
    const float* A_log  = (const float*)d_in[11];
    const float* D_par  = (const float*)d_in[12];
    const float* W_out  = (const float*)d_in[13];
    float* out = (float*)d_out;

    // ---- workspace (~169 MB) ----
    char* ws = (char*)d_ws;
    size_t off = 0;
    ushort_t* wb_in  = (ushort_t*)(ws + off); off += (size_t)1024 * 256 * 2;
    ushort_t* wb_x   = (ushort_t*)(ws + off); off += (size_t)144 * 512 * 2;
    ushort_t* wb_out = (ushort_t*)(ws + off); off += (size_t)256 * 512 * 2;
    const size_t R0 = (size_t)MROWS * DIMC * 2;
    const size_t R1 = (size_t)MROWS * 512 * 2;
    ushort_t* r0 = (ushort_t*)(ws + off); off += R0;   // xm -> xdbl -> outm
    ushort_t* r1 = (ushort_t*)(ws + off); off += R1;   // xhalf -> dt_T
    ushort_t* r2 = (ushort_t*)(ws + off); off += R1;   // z
    ushort_t* r3 = (ushort_t*)(ws + off); off += R1;   // xc -> w_T -> ys
    ushort_t* r4 = (ushort_t*)(ws + off); off += R1;   // u_T -> ysT (in place)
    f32x4*    BCfI = (f32x4*)(ws + off);  off += (size_t)MROWS * 64 * 8;  // 16.8 MB

    ushort_t* xm    = r0;
    ushort_t* xdbl  = r0;
    ushort_t* outm  = r0;
    ushort_t* xhalf = r1;
    ushort_t* dt_T  = r1;
    ushort_t* zb    = r2;
    ushort_t* xc    = r3;
    ushort_t* w_T   = r3;
    ushort_t* ys    = r3;
    ushort_t* u_T   = r4;

    // A. merged: weight cvt + LayerNorm + dual-order xm (one launch)
    const int ncvt = 1024 * 256 + 144 * 512 + 256 * 512;
    const int cvtblk = (ncvt + 255) / 256;
    hipLaunchKernelGGL(cvt_ln1, dim3(16384 + cvtblk), dim3(256), 0, stream,
                       x, ln1_w, ln1_b, xm, W_in, wb_in, W_x, wb_x, W_out, wb_out);
    // B. one launch: cols<512 -> xhalf, cols>=512 -> zb   (XCD-swizzled)
    hipLaunchKernelGGL(gemm128_split, dim3(MROWS / 128, 8), dim3(256), 0, stream,
                       xm, wb_in, xhalf, zb);
    // C. tiled conv + SiLU: xhalf -> xc[bt,d] + u_T[b,d,t]
    hipLaunchKernelGGL(conv_silu_t, dim3(MROWS / 64, 8), dim3(256), 0, stream,
                       xhalf, conv_w, conv_b, xc, u_T);
    // D. x_dbl = xc @ W_x^T   (N=144, K=512)   (XCD-swizzled)
    hipLaunchKernelGGL(gemm128, dim3(MROWS / 128, 2), dim3(256), 0, stream,
                       xc, wb_x, xdbl, MROWS, 144, 512);
    // E. dt/w (+ pair-interleaved, state-permuted B/C unpack)
    hipLaunchKernelGGL(dt_sp_t, dim3(MROWS / 64, 8), dim3(256), 0, stream,
                       xdbl, W_dt, b_dt, u_T, dt_T, w_T, BCfI);
    // F. selective scan v20: asm-pinned pipelined direct-global
    hipLaunchKernelGGL(scan20, dim3(BS2 * 512 / 4), dim3(256), 0, stream,
                       dt_T, u_T, w_T, BCfI, A_log, D_par);
    // G. gate + transpose: ys[bt,d] = ysT * silu(z)
    hipLaunchKernelGGL(gate_t, dim3(MROWS / 64, 8), dim3(256), 0, stream,
                       u_T, zb, ys);
    // H. outm = ys @ W_out^T   (N=256, K=512)   (XCD-swizzled)
    hipLaunchKernelGGL(gemm128, dim3(MROWS / 128, 2), dim3(256), 0, stream,
                       ys, wb_out, outm, MROWS, 256, 512);
    // I. final LN + transpose combine + residual (fp32 out)
    hipLaunchKernelGGL(final_ln_add, dim3(4 * LSEQ), dim3(256), 0, stream,
                       outm, x, ln2_w, ln2_b, out);
}